// Round 9
// baseline (244.568 us; speedup 1.0000x reference)
//
#include <hip/hip_runtime.h>
#include <math.h>

#define NB   256
#define PTS  512
#define EMB  12
#define NHD  4

typedef short short8v __attribute__((ext_vector_type(8)));
typedef float floatx4 __attribute__((ext_vector_type(4)));

union U16 { uint4 u; short8v s; };

// float -> bf16 bits (round to nearest even), low 16 of return
__device__ __forceinline__ unsigned bf16rne(float x) {
  union { float f; unsigned u; } v; v.f = x;
  return (v.u + 0x7FFFu + ((v.u >> 16) & 1u)) >> 16;
}

// ---------------- block-wide reduction of N floats over NW waves ----------------
template<int N, int NW>
__device__ __forceinline__ void block_reduce(float* v, float* sred, int t) {
  const int lane = t & 63;
  const int wv   = t >> 6;
  #pragma unroll
  for (int i = 0; i < N; ++i) {
    float s = v[i];
    #pragma unroll
    for (int off = 32; off > 0; off >>= 1) s += __shfl_down(s, off, 64);
    if (lane == 0) sred[wv * N + i] = s;
  }
  __syncthreads();
  #pragma unroll
  for (int i = 0; i < N; ++i) {
    float s = 0.f;
    #pragma unroll
    for (int w = 0; w < NW; ++w) s += sred[w * N + i];
    v[i] = s;
  }
  __syncthreads();
}

// ---------------- one MHA layer via mfma_f32_16x16x32_bf16 (layout verified R6-R8) ----------------
// 1024 threads: t<512 stage K+V for point p=t&511 (reads kvin); t>=512 stage Q (reads qin).
// Sᵀ = K·Qᵀ; exp(Sᵀ) feeds PV's A operand straight from registers; V ones-column = denom.
// Epilogue (normalize + out-proj into outv) computed ONLY where do_epi - halves liveness.
__device__ __forceinline__ void mha_mfma(
    const float* qin, const float* kvin, float* outv, bool do_epi,
    const float* __restrict__ w_in, const float* __restrict__ b_in,
    const float* __restrict__ w_out, const float* __restrict__ b_out,
    uint4* skA, uint4* sqQ, unsigned short* svB, float* sO, int t)
{
  __syncthreads();   // previous layer's consumers of all LDS regions are done

  const int p = t & 511;
  if (t < 512) {
    // ---- stage K and V for point p (per-head to keep liveness low) ----
    const int kg = p >> 5, oddt = (p >> 4) & 1, kap = p & 15;   // 32-key group / half / slot
    uint2* skA2 = (uint2*)skA;
    const int g = p & 31, odd = g >> 4, sub = g & 15;
    const int q4 = sub >> 2, jj = (sub & 3) + 4 * odd;
    #pragma unroll
    for (int h = 0; h < NHD; ++h) {
      float k0 = b_in[EMB + h*3+0],   k1 = b_in[EMB + h*3+1],   k2 = b_in[EMB + h*3+2];
      float v0 = b_in[2*EMB + h*3+0], v1 = b_in[2*EMB + h*3+1], v2 = b_in[2*EMB + h*3+2];
      #pragma unroll
      for (int f = 0; f < EMB; ++f) {
        float x = kvin[f];
        k0 = fmaf(x, w_in[(EMB + h*3+0) * EMB + f], k0);
        k1 = fmaf(x, w_in[(EMB + h*3+1) * EMB + f], k1);
        k2 = fmaf(x, w_in[(EMB + h*3+2) * EMB + f], k2);
        v0 = fmaf(x, w_in[(2*EMB + h*3+0) * EMB + f], v0);
        v1 = fmaf(x, w_in[(2*EMB + h*3+1) * EMB + f], v1);
        v2 = fmaf(x, w_in[(2*EMB + h*3+2) * EMB + f], v2);
      }
      skA2[((kg * NHD + h) * 16 + kap) * 2 + oddt] =
          make_uint2(bf16rne(k0) | (bf16rne(k1) << 16), bf16rne(k2));
      svB[(((kg * NHD + h) * 4 + q4) * 4 + 0) * 8 + jj] = (unsigned short)bf16rne(v0);
      svB[(((kg * NHD + h) * 4 + q4) * 4 + 1) * 8 + jj] = (unsigned short)bf16rne(v1);
      svB[(((kg * NHD + h) * 4 + q4) * 4 + 2) * 8 + jj] = (unsigned short)bf16rne(v2);
      svB[(((kg * NHD + h) * 4 + q4) * 4 + 3) * 8 + jj] = (unsigned short)0x3F80u; // 1.0 -> denom
    }
  } else {
    // ---- stage Q (scaled) for point p ----
    const float qs = 0.5773502691896258f * 1.4426950408889634f; // 1/sqrt(3)*log2(e)
    const int kt = p >> 4, kap = p & 15;
    #pragma unroll
    for (int h = 0; h < NHD; ++h) {
      float q0 = b_in[h*3+0], q1 = b_in[h*3+1], q2 = b_in[h*3+2];
      #pragma unroll
      for (int f = 0; f < EMB; ++f) {
        float x = qin[f];
        q0 = fmaf(x, w_in[(h*3+0) * EMB + f], q0);
        q1 = fmaf(x, w_in[(h*3+1) * EMB + f], q1);
        q2 = fmaf(x, w_in[(h*3+2) * EMB + f], q2);
      }
      q0 *= qs; q1 *= qs; q2 *= qs;
      sqQ[(kt * NHD + h) * 16 + kap] =
          make_uint4(bf16rne(q0) | (bf16rne(q1) << 16), bf16rne(q2), 0u, 0u);
    }
  }
  __syncthreads();

  const int lane = t & 63, wv = t >> 6;          // wv 0..15
  const int lq = lane >> 4, ln = lane & 15;

  // ---- Qᵀ fragments for this wave's 2 row-tiles (quads >= 1 zeroed) ----
  short8v qf[2][NHD];
  #pragma unroll
  for (int i = 0; i < 2; ++i)
    #pragma unroll
    for (int h = 0; h < NHD; ++h) {
      U16 u; u.u = sqQ[((wv * 2 + i) * NHD + h) * 16 + ln];
      if (lq != 0) u.u = make_uint4(0u, 0u, 0u, 0u);
      qf[i][h] = u.s;
    }

  floatx4 oacc[2][NHD];
  #pragma unroll
  for (int i = 0; i < 2; ++i)
    #pragma unroll
    for (int h = 0; h < NHD; ++h) {
      floatx4 z = {0.f, 0.f, 0.f, 0.f};
      oacc[i][h] = z;
    }

  const uint4* svB4 = (const uint4*)svB;
  for (int kg = 0; kg < 16; ++kg) {
    #pragma unroll
    for (int h = 0; h < NHD; ++h) {
      uint4 kp = skA[(kg * NHD + h) * 16 + ln];                  // K even+odd pair (bcast x4)
      U16 vf; vf.u = svB4[((kg * NHD + h) * 4 + lq) * 4 + (ln & 3)];
      U16 fe; fe.u = make_uint4(kp.x, kp.y, 0u, 0u);             // even-tile A frag
      U16 fo; fo.u = make_uint4(kp.z, kp.w, 0u, 0u);             // odd-tile A frag
      #pragma unroll
      for (int i = 0; i < 2; ++i) {
        floatx4 zc = {0.f, 0.f, 0.f, 0.f};
        floatx4 se = __builtin_amdgcn_mfma_f32_16x16x32_bf16(fe.s, qf[i][h], zc, 0, 0, 0);
        floatx4 so = __builtin_amdgcn_mfma_f32_16x16x32_bf16(fo.s, qf[i][h], zc, 0, 0, 0);
        unsigned p0 = __float_as_uint(__builtin_amdgcn_exp2f(se[0]));
        unsigned p1 = __float_as_uint(__builtin_amdgcn_exp2f(se[1]));
        unsigned p2 = __float_as_uint(__builtin_amdgcn_exp2f(se[2]));
        unsigned p3 = __float_as_uint(__builtin_amdgcn_exp2f(se[3]));
        unsigned p4 = __float_as_uint(__builtin_amdgcn_exp2f(so[0]));
        unsigned p5 = __float_as_uint(__builtin_amdgcn_exp2f(so[1]));
        unsigned p6 = __float_as_uint(__builtin_amdgcn_exp2f(so[2]));
        unsigned p7 = __float_as_uint(__builtin_amdgcn_exp2f(so[3]));
        U16 pf;   // one v_perm each: low short = bf16(first), high = bf16(second)
        pf.u.x = __builtin_amdgcn_perm(p1, p0, 0x07060302u);  // slots j=0,1
        pf.u.y = __builtin_amdgcn_perm(p3, p2, 0x07060302u);  // slots j=2,3
        pf.u.z = __builtin_amdgcn_perm(p5, p4, 0x07060302u);  // slots j=4,5
        pf.u.w = __builtin_amdgcn_perm(p7, p6, 0x07060302u);  // slots j=6,7
        oacc[i][h] = __builtin_amdgcn_mfma_f32_16x16x32_bf16(pf.s, vf.s, oacc[i][h], 0, 0, 0);
      }
    }
  }

  // ---- redistribute O (C-layout, cols 0..3 valid) to per-row layout in LDS ----
  if (ln < 4) {
    #pragma unroll
    for (int i = 0; i < 2; ++i)
      #pragma unroll
      for (int h = 0; h < NHD; ++h)
        #pragma unroll
        for (int r = 0; r < 4; ++r)
          sO[((wv * 2 + i) * 16 + lq * 4 + r) * 16 + h * 4 + ln] = oacc[i][h][r];
  }
  __syncthreads();

  // ---- normalize + out-projection for point p (only the half that needs it) ----
  if (do_epi) {
    const float4* sr = (const float4*)(sO + p * 16);
    float o[EMB];
    #pragma unroll
    for (int h = 0; h < NHD; ++h) {
      float4 Oh = sr[h];
      float inv = 1.0f / fmaxf(Oh.w, 1e-20f);   // inert guard
      o[h*3+0] = Oh.x * inv; o[h*3+1] = Oh.y * inv; o[h*3+2] = Oh.z * inv;
    }
    #pragma unroll
    for (int e = 0; e < EMB; ++e) {
      float s = b_out[e];
      #pragma unroll
      for (int f = 0; f < EMB; ++f) s = fmaf(o[f], w_out[e * EMB + f], s);
      outv[e] = s;
    }
  }
}

__global__ __launch_bounds__(1024, 4)
void pcr_kernel(const float* __restrict__ x_orig, const float* __restrict__ y_orig,
                const float* __restrict__ lin_in_w,  const float* __restrict__ lin_in_b,
                const float* __restrict__ lin_in2_w, const float* __restrict__ lin_in2_b,
                const float* __restrict__ attn_in_w,  const float* __restrict__ attn_in_b,
                const float* __restrict__ attn_out_w, const float* __restrict__ attn_out_b,
                const float* __restrict__ attn2_in_w,  const float* __restrict__ attn2_in_b,
                const float* __restrict__ attn2_out_w, const float* __restrict__ attn2_out_b,
                const float* __restrict__ cross_in_w,  const float* __restrict__ cross_in_b,
                const float* __restrict__ cross_out_w, const float* __restrict__ cross_out_b,
                const float* __restrict__ lin_out_w, const float* __restrict__ lin_out_b,
                float* __restrict__ out)
{
  __shared__ __align__(16) uint4 skA[16 * NHD * 16];                   // [kg][h][slot] K pairs
  __shared__ __align__(16) uint4 sqQ[32 * NHD * 16];                   // [rt][h][row]
  __shared__ __align__(16) unsigned short svB[16 * NHD * 4 * 4 * 8];   // [kg][h][lq][n][j]
  __shared__ __align__(16) float sO[PTS * 16];
  __shared__ float sred[16 * 12];

  const int b = blockIdx.x;
  const int t = threadIdx.x;
  const int p = t & 511;
  const bool own = (t < 512);
  const int base = (b * PTS + p) * 3;

  // ---- center x and y (per-batch mean; only t<512 contribute to sums) ----
  float x3[3], ymean[3], y3[3];
  {
    float xl[3], yl[3];
    #pragma unroll
    for (int i = 0; i < 3; ++i) { xl[i] = x_orig[base + i]; yl[i] = y_orig[base + i]; }
    float r6[6];
    #pragma unroll
    for (int i = 0; i < 3; ++i) {
      r6[i]     = own ? xl[i] : 0.f;
      r6[3 + i] = own ? yl[i] : 0.f;
    }
    block_reduce<6, 16>(r6, sred, t);
    #pragma unroll
    for (int i = 0; i < 3; ++i) {
      x3[i]    = xl[i] - r6[i] * (1.f / PTS);
      ymean[i] = r6[3 + i] * (1.f / PTS);
      y3[i]    = yl[i] - ymean[i];
    }
  }

  // ---- input linears (3 -> 12): a = xi, b = yi ----
  float a[EMB], bb[EMB];
  #pragma unroll
  for (int e = 0; e < EMB; ++e) {
    float sx = lin_in_b[e], sy = lin_in2_b[e];
    #pragma unroll
    for (int i = 0; i < 3; ++i) {
      sx = fmaf(x3[i], lin_in_w[e * 3 + i], sx);
      sy = fmaf(y3[i], lin_in2_w[e * 3 + i], sy);
    }
    a[e] = sx; bb[e] = sy;
  }

  // ---- three attention layers (in-place outputs; ownership-specialized epilogues) ----
  // L1 self(x): out needed only by t>=512 (L3's Q-staging)
  mha_mfma(a, a, a, !own, attn_in_w,  attn_in_b,  attn_out_w,  attn_out_b,
           skA, sqQ, svB, sO, t);
  // L2 self(y): out needed only by t<512 (L3's KV-staging)
  mha_mfma(bb, bb, bb, own, attn2_in_w, attn2_in_b, attn2_out_w, attn2_out_b,
           skA, sqQ, svB, sO, t);
  // L3 cross(q=x1, kv=y1): out needed only by t<512 (Kabsch)
  mha_mfma(a, bb, a, own, cross_in_w, cross_in_b, cross_out_w, cross_out_b,
           skA, sqQ, svB, sO, t);

  // ---- output linear (12 -> 3); bp = coords + x ----
  float bp[3];
  #pragma unroll
  for (int d = 0; d < 3; ++d) {
    float c = lin_out_b[d];
    #pragma unroll
    for (int e = 0; e < EMB; ++e) c = fmaf(a[e], lin_out_w[d * EMB + e], c);
    bp[d] = c + x3[d];
  }

  // ---- Kabsch: H[i][j] = sum_p x[p,i]*bp[p,j] (sum_p x = 0), plus sum bp ----
  float r12[12];
  #pragma unroll
  for (int i = 0; i < 3; ++i)
    #pragma unroll
    for (int j = 0; j < 3; ++j) r12[i * 3 + j] = own ? x3[i] * bp[j] : 0.f;
  #pragma unroll
  for (int j = 0; j < 3; ++j) r12[9 + j] = own ? bp[j] : 0.f;
  block_reduce<12, 16>(r12, sred, t);

  if (own) {
    float cA[3];
    #pragma unroll
    for (int j = 0; j < 3; ++j) cA[j] = r12[9 + j] * (1.f / PTS);

    // ---- R = polar factor of H via determinant-scaled Newton (== U @ Vt) ----
    float a00 = r12[0], a01 = r12[1], a02 = r12[2];
    float a10 = r12[3], a11 = r12[4], a12_ = r12[5];
    float a20 = r12[6], a21 = r12[7], a22 = r12[8];

    float c0 = fabsf(a00) + fabsf(a10) + fabsf(a20);
    float c1 = fabsf(a01) + fabsf(a11) + fabsf(a21);
    float c2 = fabsf(a02) + fabsf(a12_) + fabsf(a22);
    float r0 = fabsf(a00) + fabsf(a01) + fabsf(a02);
    float r1 = fabsf(a10) + fabsf(a11) + fabsf(a12_);
    float r2 = fabsf(a20) + fabsf(a21) + fabsf(a22);
    float fsc = rsqrtf(fmaxf(c0, fmaxf(c1, c2)) * fmaxf(r0, fmaxf(r1, r2)) + 1e-30f);
    a00 *= fsc; a01 *= fsc; a02 *= fsc;
    a10 *= fsc; a11 *= fsc; a12_ *= fsc;
    a20 *= fsc; a21 *= fsc; a22 *= fsc;

    #pragma unroll 1
    for (int it = 0; it < 12; ++it) {
      float C00 = a11*a22 - a12_*a21;
      float C01 = a12_*a20 - a10*a22;
      float C02 = a10*a21 - a11*a20;
      float C10 = a02*a21 - a01*a22;
      float C11 = a00*a22 - a02*a20;
      float C12 = a01*a20 - a00*a21;
      float C20 = a01*a12_ - a02*a11;
      float C21 = a02*a10 - a00*a12_;
      float C22 = a00*a11 - a01*a10;
      float det = a00*C00 + a01*C01 + a02*C02;
      float g  = 1.0f / cbrtf(fabsf(det) + 1e-30f);
      float dg = det * g;
      dg = copysignf(fmaxf(fabsf(dg), 1e-25f), dg);   // inert guard
      float id = 0.5f / dg;
      float gh = 0.5f * g;
      a00 = gh*a00 + C00*id; a01 = gh*a01 + C01*id; a02 = gh*a02 + C02*id;
      a10 = gh*a10 + C10*id; a11 = gh*a11 + C11*id; a12_ = gh*a12_ + C12*id;
      a20 = gh*a20 + C20*id; a21 = gh*a21 + C21*id; a22 = gh*a22 + C22*id;
    }

    // ---- out = x @ R + t + y_translate ----
    float o0 = fmaf(x3[0], a00, fmaf(x3[1], a10, fmaf(x3[2], a20, cA[0] + ymean[0])));
    float o1 = fmaf(x3[0], a01, fmaf(x3[1], a11, fmaf(x3[2], a21, cA[1] + ymean[1])));
    float o2 = fmaf(x3[0], a02, fmaf(x3[1], a12_, fmaf(x3[2], a22, cA[2] + ymean[2])));
    out[base + 0] = o0;
    out[base + 1] = o1;
    out[base + 2] = o2;
  }
}

extern "C" void kernel_launch(void* const* d_in, const int* in_sizes, int n_in,
                              void* d_out, int out_size, void* d_ws, size_t ws_size,
                              hipStream_t stream) {
  const float* p[20];
  for (int i = 0; i < 20; ++i) p[i] = (const float*)d_in[i];
  pcr_kernel<<<dim3(NB), dim3(1024), 0, stream>>>(
      p[0], p[1], p[2], p[3], p[4], p[5], p[6], p[7], p[8], p[9],
      p[10], p[11], p[12], p[13], p[14], p[15], p[16], p[17], p[18], p[19],
      (float*)d_out);
}

// Round 10
// 238.656 us; speedup vs baseline: 1.0248x; 1.0248x over previous
//
#include <hip/hip_runtime.h>
#include <math.h>

#define NB   256
#define PTS  512
#define EMB  12
#define NHD  4

typedef short short8v __attribute__((ext_vector_type(8)));
typedef float floatx4 __attribute__((ext_vector_type(4)));

union U16 { uint4 u; short8v s; };

// float -> bf16 bits (round to nearest even), low 16 of return
__device__ __forceinline__ unsigned bf16rne(float x) {
  union { float f; unsigned u; } v; v.f = x;
  return (v.u + 0x7FFFu + ((v.u >> 16) & 1u)) >> 16;
}

// ---------------- block-wide reduction of N floats over NW waves ----------------
template<int N, int NW>
__device__ __forceinline__ void block_reduce(float* v, float* sred, int t) {
  const int lane = t & 63;
  const int wv   = t >> 6;
  #pragma unroll
  for (int i = 0; i < N; ++i) {
    float s = v[i];
    #pragma unroll
    for (int off = 32; off > 0; off >>= 1) s += __shfl_down(s, off, 64);
    if (lane == 0) sred[wv * N + i] = s;
  }
  __syncthreads();
  #pragma unroll
  for (int i = 0; i < N; ++i) {
    float s = 0.f;
    #pragma unroll
    for (int w = 0; w < NW; ++w) s += sred[w * N + i];
    v[i] = s;
  }
  __syncthreads();
}

// ---------------- one MHA layer via mfma_f32_16x16x32_bf16 (layout verified R6-R9) ----------------
// Activations live in LDS (qsrc/kvsrc rows of 12 floats). 1024 threads:
//   t<512 stage K+V for point p=t&511 from kvsrc; t>=512 stage Q from qsrc.
// Sᵀ = K·Qᵀ; exp(Sᵀ) feeds PV's A operand straight from registers; V ones-column = denom.
// Epilogue: t<512 normalize + out-project point p; write to dst row (or outv regs if dst==null).
__device__ __forceinline__ void mha_mfma(
    const float* qsrc, const float* kvsrc, float* dst, float* outv,
    const float* __restrict__ w_in, const float* __restrict__ b_in,
    const float* __restrict__ w_out, const float* __restrict__ b_out,
    uint4* skA, uint4* sqQ, unsigned short* svB, float* sO, float* sred, int t)
{
  __syncthreads();   // previous layer's consumers/writers of all LDS regions are done

  const int p = t & 511;
  if (t < 512) {
    // ---- stage K and V for point p from kvsrc row ----
    float xr[EMB];
    {
      const float4* r4 = (const float4*)(kvsrc + p * EMB);
      float4 r0 = r4[0], r1 = r4[1], r2 = r4[2];
      xr[0]=r0.x; xr[1]=r0.y; xr[2]=r0.z; xr[3]=r0.w;
      xr[4]=r1.x; xr[5]=r1.y; xr[6]=r1.z; xr[7]=r1.w;
      xr[8]=r2.x; xr[9]=r2.y; xr[10]=r2.z; xr[11]=r2.w;
    }
    const int kg = p >> 5, oddt = (p >> 4) & 1, kap = p & 15;   // 32-key group / half / slot
    uint2* skA2 = (uint2*)skA;
    const int g = p & 31, odd = g >> 4, sub = g & 15;
    const int q4 = sub >> 2, jj = (sub & 3) + 4 * odd;
    #pragma unroll
    for (int h = 0; h < NHD; ++h) {
      float k0 = b_in[EMB + h*3+0],   k1 = b_in[EMB + h*3+1],   k2 = b_in[EMB + h*3+2];
      float v0 = b_in[2*EMB + h*3+0], v1 = b_in[2*EMB + h*3+1], v2 = b_in[2*EMB + h*3+2];
      #pragma unroll
      for (int f = 0; f < EMB; ++f) {
        float x = xr[f];
        k0 = fmaf(x, w_in[(EMB + h*3+0) * EMB + f], k0);
        k1 = fmaf(x, w_in[(EMB + h*3+1) * EMB + f], k1);
        k2 = fmaf(x, w_in[(EMB + h*3+2) * EMB + f], k2);
        v0 = fmaf(x, w_in[(2*EMB + h*3+0) * EMB + f], v0);
        v1 = fmaf(x, w_in[(2*EMB + h*3+1) * EMB + f], v1);
        v2 = fmaf(x, w_in[(2*EMB + h*3+2) * EMB + f], v2);
      }
      skA2[((kg * NHD + h) * 16 + kap) * 2 + oddt] =
          make_uint2(bf16rne(k0) | (bf16rne(k1) << 16), bf16rne(k2));
      svB[(((kg * NHD + h) * 4 + q4) * 4 + 0) * 8 + jj] = (unsigned short)bf16rne(v0);
      svB[(((kg * NHD + h) * 4 + q4) * 4 + 1) * 8 + jj] = (unsigned short)bf16rne(v1);
      svB[(((kg * NHD + h) * 4 + q4) * 4 + 2) * 8 + jj] = (unsigned short)bf16rne(v2);
      svB[(((kg * NHD + h) * 4 + q4) * 4 + 3) * 8 + jj] = (unsigned short)0x3F80u; // 1.0 -> denom
    }
  } else {
    // ---- stage Q (scaled) for point p from qsrc row ----
    float xr[EMB];
    {
      const float4* r4 = (const float4*)(qsrc + p * EMB);
      float4 r0 = r4[0], r1 = r4[1], r2 = r4[2];
      xr[0]=r0.x; xr[1]=r0.y; xr[2]=r0.z; xr[3]=r0.w;
      xr[4]=r1.x; xr[5]=r1.y; xr[6]=r1.z; xr[7]=r1.w;
      xr[8]=r2.x; xr[9]=r2.y; xr[10]=r2.z; xr[11]=r2.w;
    }
    const float qs = 0.5773502691896258f * 1.4426950408889634f; // 1/sqrt(3)*log2(e)
    const int kt = p >> 4, kap = p & 15;
    #pragma unroll
    for (int h = 0; h < NHD; ++h) {
      float q0 = b_in[h*3+0], q1 = b_in[h*3+1], q2 = b_in[h*3+2];
      #pragma unroll
      for (int f = 0; f < EMB; ++f) {
        float x = xr[f];
        q0 = fmaf(x, w_in[(h*3+0) * EMB + f], q0);
        q1 = fmaf(x, w_in[(h*3+1) * EMB + f], q1);
        q2 = fmaf(x, w_in[(h*3+2) * EMB + f], q2);
      }
      q0 *= qs; q1 *= qs; q2 *= qs;
      sqQ[(kt * NHD + h) * 16 + kap] =
          make_uint4(bf16rne(q0) | (bf16rne(q1) << 16), bf16rne(q2), 0u, 0u);
    }
  }
  __syncthreads();

  const int lane = t & 63, wv = t >> 6;          // wv 0..15
  const int lq = lane >> 4, ln = lane & 15;

  // ---- Qᵀ fragments for this wave's 2 row-tiles (quads >= 1 zeroed) ----
  short8v qf[2][NHD];
  #pragma unroll
  for (int i = 0; i < 2; ++i)
    #pragma unroll
    for (int h = 0; h < NHD; ++h) {
      U16 u; u.u = sqQ[((wv * 2 + i) * NHD + h) * 16 + ln];
      if (lq != 0) u.u = make_uint4(0u, 0u, 0u, 0u);
      qf[i][h] = u.s;
    }

  floatx4 oacc[2][NHD];
  #pragma unroll
  for (int i = 0; i < 2; ++i)
    #pragma unroll
    for (int h = 0; h < NHD; ++h) {
      floatx4 z = {0.f, 0.f, 0.f, 0.f};
      oacc[i][h] = z;
    }

  const uint4* svB4 = (const uint4*)svB;
  for (int kg = 0; kg < 16; ++kg) {
    #pragma unroll
    for (int h = 0; h < NHD; ++h) {
      uint4 kp = skA[(kg * NHD + h) * 16 + ln];                  // K even+odd pair (bcast x4)
      U16 vf; vf.u = svB4[((kg * NHD + h) * 4 + lq) * 4 + (ln & 3)];
      U16 fe; fe.u = make_uint4(kp.x, kp.y, 0u, 0u);             // even-tile A frag
      U16 fo; fo.u = make_uint4(kp.z, kp.w, 0u, 0u);             // odd-tile A frag
      #pragma unroll
      for (int i = 0; i < 2; ++i) {
        floatx4 zc = {0.f, 0.f, 0.f, 0.f};
        floatx4 se = __builtin_amdgcn_mfma_f32_16x16x32_bf16(fe.s, qf[i][h], zc, 0, 0, 0);
        floatx4 so = __builtin_amdgcn_mfma_f32_16x16x32_bf16(fo.s, qf[i][h], zc, 0, 0, 0);
        unsigned p0 = __float_as_uint(__builtin_amdgcn_exp2f(se[0]));
        unsigned p1 = __float_as_uint(__builtin_amdgcn_exp2f(se[1]));
        unsigned p2 = __float_as_uint(__builtin_amdgcn_exp2f(se[2]));
        unsigned p3 = __float_as_uint(__builtin_amdgcn_exp2f(se[3]));
        unsigned p4 = __float_as_uint(__builtin_amdgcn_exp2f(so[0]));
        unsigned p5 = __float_as_uint(__builtin_amdgcn_exp2f(so[1]));
        unsigned p6 = __float_as_uint(__builtin_amdgcn_exp2f(so[2]));
        unsigned p7 = __float_as_uint(__builtin_amdgcn_exp2f(so[3]));
        U16 pf;   // one v_perm each: low short = bf16(first), high = bf16(second)
        pf.u.x = __builtin_amdgcn_perm(p1, p0, 0x07060302u);  // slots j=0,1
        pf.u.y = __builtin_amdgcn_perm(p3, p2, 0x07060302u);  // slots j=2,3
        pf.u.z = __builtin_amdgcn_perm(p5, p4, 0x07060302u);  // slots j=4,5
        pf.u.w = __builtin_amdgcn_perm(p7, p6, 0x07060302u);  // slots j=6,7
        oacc[i][h] = __builtin_amdgcn_mfma_f32_16x16x32_bf16(pf.s, vf.s, oacc[i][h], 0, 0, 0);
      }
    }
  }

  // ---- redistribute O (C-layout, cols 0..3 valid) to per-row layout in LDS ----
  if (ln < 4) {
    #pragma unroll
    for (int i = 0; i < 2; ++i)
      #pragma unroll
      for (int h = 0; h < NHD; ++h)
        #pragma unroll
        for (int r = 0; r < 4; ++r)
          sO[((wv * 2 + i) * 16 + lq * 4 + r) * 16 + h * 4 + ln] = oacc[i][h][r];
  }
  __syncthreads();

  // ---- normalize + out-projection for point p (t<512 only); write to dst or outv ----
  if (t < 512) {
    const float4* sr = (const float4*)(sO + p * 16);
    float o[EMB];
    #pragma unroll
    for (int h = 0; h < NHD; ++h) {
      float4 Oh = sr[h];
      float inv = 1.0f / fmaxf(Oh.w, 1e-20f);   // inert guard
      o[h*3+0] = Oh.x * inv; o[h*3+1] = Oh.y * inv; o[h*3+2] = Oh.z * inv;
    }
    float r[EMB];
    #pragma unroll
    for (int e = 0; e < EMB; ++e) {
      float s = b_out[e];
      #pragma unroll
      for (int f = 0; f < EMB; ++f) s = fmaf(o[f], w_out[e * EMB + f], s);
      r[e] = s;
    }
    if (dst) {
      float4* d4 = (float4*)(dst + p * EMB);
      d4[0] = make_float4(r[0], r[1], r[2],  r[3]);
      d4[1] = make_float4(r[4], r[5], r[6],  r[7]);
      d4[2] = make_float4(r[8], r[9], r[10], r[11]);
    } else {
      #pragma unroll
      for (int e = 0; e < EMB; ++e) outv[e] = r[e];
    }
  }
}

__global__ __launch_bounds__(1024, 4)
void pcr_kernel(const float* __restrict__ x_orig, const float* __restrict__ y_orig,
                const float* __restrict__ lin_in_w,  const float* __restrict__ lin_in_b,
                const float* __restrict__ lin_in2_w, const float* __restrict__ lin_in2_b,
                const float* __restrict__ attn_in_w,  const float* __restrict__ attn_in_b,
                const float* __restrict__ attn_out_w, const float* __restrict__ attn_out_b,
                const float* __restrict__ attn2_in_w,  const float* __restrict__ attn2_in_b,
                const float* __restrict__ attn2_out_w, const float* __restrict__ attn2_out_b,
                const float* __restrict__ cross_in_w,  const float* __restrict__ cross_in_b,
                const float* __restrict__ cross_out_w, const float* __restrict__ cross_out_b,
                const float* __restrict__ lin_out_w, const float* __restrict__ lin_out_b,
                float* __restrict__ out)
{
  __shared__ __align__(16) float sX[PTS * EMB];                        // 24 KB x-path activations
  __shared__ __align__(16) float sY[PTS * EMB];                        // 24 KB y-path activations
  __shared__ __align__(16) uint4 skA[16 * NHD * 16];                   // 16 KB K pairs
  __shared__ __align__(16) uint4 sqQ[32 * NHD * 16];                   // 32 KB Q frags
  __shared__ __align__(16) unsigned short svB[16 * NHD * 4 * 4 * 8];   // 16 KB V frags
  __shared__ __align__(16) float sO[PTS * 16];                         // 32 KB O rows
  __shared__ float sred[16 * 12];

  const int b = blockIdx.x;
  const int t = threadIdx.x;
  const int p = t & 511;
  const bool own = (t < 512);
  const int base = (b * PTS + p) * 3;

  // ---- center x and y (per-batch mean; only t<512 contribute to sums) ----
  float x3[3], ymean[3];
  {
    float xl[3], yl[3];
    #pragma unroll
    for (int i = 0; i < 3; ++i) { xl[i] = x_orig[base + i]; yl[i] = y_orig[base + i]; }
    float r6[6];
    #pragma unroll
    for (int i = 0; i < 3; ++i) {
      r6[i]     = own ? xl[i] : 0.f;
      r6[3 + i] = own ? yl[i] : 0.f;
    }
    block_reduce<6, 16>(r6, sred, t);
    float y3[3];
    #pragma unroll
    for (int i = 0; i < 3; ++i) {
      x3[i]    = xl[i] - r6[i] * (1.f / PTS);
      ymean[i] = r6[3 + i] * (1.f / PTS);
      y3[i]    = yl[i] - ymean[i];
    }
    // ---- input linears (3 -> 12): t<512 write sX from x; t>=512 write sY from y ----
    const float* w = own ? lin_in_w : lin_in2_w;
    const float* bi = own ? lin_in_b : lin_in2_b;
    const float* src = own ? x3 : y3;
    float* dst = own ? sX : sY;
    float r[EMB];
    #pragma unroll
    for (int e = 0; e < EMB; ++e) {
      float s = bi[e];
      #pragma unroll
      for (int i = 0; i < 3; ++i) s = fmaf(src[i], w[e * 3 + i], s);
      r[e] = s;
    }
    float4* d4 = (float4*)(dst + p * EMB);
    d4[0] = make_float4(r[0], r[1], r[2],  r[3]);
    d4[1] = make_float4(r[4], r[5], r[6],  r[7]);
    d4[2] = make_float4(r[8], r[9], r[10], r[11]);
  }

  // ---- three attention layers (activations carried in LDS) ----
  float o12[EMB] = {0,0,0,0,0,0,0,0,0,0,0,0};
  // L1 self(x): q,kv from sX; out -> sX
  mha_mfma(sX, sX, sX, nullptr, attn_in_w,  attn_in_b,  attn_out_w,  attn_out_b,
           skA, sqQ, svB, sO, sred, t);
  // L2 self(y): q,kv from sY; out -> sY
  mha_mfma(sY, sY, sY, nullptr, attn2_in_w, attn2_in_b, attn2_out_w, attn2_out_b,
           skA, sqQ, svB, sO, sred, t);
  // L3 cross(q=x1, kv=y1): out kept in registers (t<512)
  mha_mfma(sX, sY, nullptr, o12, cross_in_w, cross_in_b, cross_out_w, cross_out_b,
           skA, sqQ, svB, sO, sred, t);

  // ---- output linear (12 -> 3); bp = coords + x ----
  float bp[3];
  #pragma unroll
  for (int d = 0; d < 3; ++d) {
    float c = lin_out_b[d];
    #pragma unroll
    for (int e = 0; e < EMB; ++e) c = fmaf(o12[e], lin_out_w[d * EMB + e], c);
    bp[d] = c + x3[d];
  }

  // ---- Kabsch: H[i][j] = sum_p x[p,i]*bp[p,j] (sum_p x = 0), plus sum bp ----
  float r12[12];
  #pragma unroll
  for (int i = 0; i < 3; ++i)
    #pragma unroll
    for (int j = 0; j < 3; ++j) r12[i * 3 + j] = own ? x3[i] * bp[j] : 0.f;
  #pragma unroll
  for (int j = 0; j < 3; ++j) r12[9 + j] = own ? bp[j] : 0.f;
  block_reduce<12, 16>(r12, sred, t);

  if (own) {
    float cA[3];
    #pragma unroll
    for (int j = 0; j < 3; ++j) cA[j] = r12[9 + j] * (1.f / PTS);

    // ---- R = polar factor of H via determinant-scaled Newton (== U @ Vt) ----
    float a00 = r12[0], a01 = r12[1], a02 = r12[2];
    float a10 = r12[3], a11 = r12[4], a12_ = r12[5];
    float a20 = r12[6], a21 = r12[7], a22 = r12[8];

    float c0 = fabsf(a00) + fabsf(a10) + fabsf(a20);
    float c1 = fabsf(a01) + fabsf(a11) + fabsf(a21);
    float c2 = fabsf(a02) + fabsf(a12_) + fabsf(a22);
    float r0 = fabsf(a00) + fabsf(a01) + fabsf(a02);
    float r1 = fabsf(a10) + fabsf(a11) + fabsf(a12_);
    float r2 = fabsf(a20) + fabsf(a21) + fabsf(a22);
    float fsc = rsqrtf(fmaxf(c0, fmaxf(c1, c2)) * fmaxf(r0, fmaxf(r1, r2)) + 1e-30f);
    a00 *= fsc; a01 *= fsc; a02 *= fsc;
    a10 *= fsc; a11 *= fsc; a12_ *= fsc;
    a20 *= fsc; a21 *= fsc; a22 *= fsc;

    #pragma unroll 1
    for (int it = 0; it < 12; ++it) {
      float C00 = a11*a22 - a12_*a21;
      float C01 = a12_*a20 - a10*a22;
      float C02 = a10*a21 - a11*a20;
      float C10 = a02*a21 - a01*a22;
      float C11 = a00*a22 - a02*a20;
      float C12 = a01*a20 - a00*a21;
      float C20 = a01*a12_ - a02*a11;
      float C21 = a02*a10 - a00*a12_;
      float C22 = a00*a11 - a01*a10;
      float det = a00*C00 + a01*C01 + a02*C02;
      float g  = 1.0f / cbrtf(fabsf(det) + 1e-30f);
      float dg = det * g;
      dg = copysignf(fmaxf(fabsf(dg), 1e-25f), dg);   // inert guard
      float id = 0.5f / dg;
      float gh = 0.5f * g;
      a00 = gh*a00 + C00*id; a01 = gh*a01 + C01*id; a02 = gh*a02 + C02*id;
      a10 = gh*a10 + C10*id; a11 = gh*a11 + C11*id; a12_ = gh*a12_ + C12*id;
      a20 = gh*a20 + C20*id; a21 = gh*a21 + C21*id; a22 = gh*a22 + C22*id;
    }

    // ---- out = x @ R + t + y_translate ----
    float o0 = fmaf(x3[0], a00, fmaf(x3[1], a10, fmaf(x3[2], a20, cA[0] + ymean[0])));
    float o1 = fmaf(x3[0], a01, fmaf(x3[1], a11, fmaf(x3[2], a21, cA[1] + ymean[1])));
    float o2 = fmaf(x3[0], a02, fmaf(x3[1], a12_, fmaf(x3[2], a22, cA[2] + ymean[2])));
    out[base + 0] = o0;
    out[base + 1] = o1;
    out[base + 2] = o2;
  }
}

extern "C" void kernel_launch(void* const* d_in, const int* in_sizes, int n_in,
                              void* d_out, int out_size, void* d_ws, size_t ws_size,
                              hipStream_t stream) {
  const float* p[20];
  for (int i = 0; i < 20; ++i) p[i] = (const float*)d_in[i];
  pcr_kernel<<<dim3(NB), dim3(1024), 0, stream>>>(
      p[0], p[1], p[2], p[3], p[4], p[5], p[6], p[7], p[8], p[9],
      p[10], p[11], p[12], p[13], p[14], p[15], p[16], p[17], p[18], p[19],
      (float*)d_out);
}

// Round 11
// 236.825 us; speedup vs baseline: 1.0327x; 1.0077x over previous
//
#include <hip/hip_runtime.h>
#include <math.h>

#define NB   256
#define PTS  512
#define EMB  12
#define NHD  4

typedef short short8v __attribute__((ext_vector_type(8)));
typedef float floatx4 __attribute__((ext_vector_type(4)));

union U16 { uint4 u; short8v s; };

// float -> bf16 bits (round to nearest even), low 16 of return
__device__ __forceinline__ unsigned bf16rne(float x) {
  union { float f; unsigned u; } v; v.f = x;
  return (v.u + 0x7FFFu + ((v.u >> 16) & 1u)) >> 16;
}

// ---------------- block-wide reduction of N floats over NW waves ----------------
template<int N, int NW>
__device__ __forceinline__ void block_reduce(float* v, float* sred, int t) {
  const int lane = t & 63;
  const int wv   = t >> 6;
  #pragma unroll
  for (int i = 0; i < N; ++i) {
    float s = v[i];
    #pragma unroll
    for (int off = 32; off > 0; off >>= 1) s += __shfl_down(s, off, 64);
    if (lane == 0) sred[wv * N + i] = s;
  }
  __syncthreads();
  #pragma unroll
  for (int i = 0; i < N; ++i) {
    float s = 0.f;
    #pragma unroll
    for (int w = 0; w < NW; ++w) s += sred[w * N + i];
    v[i] = s;
  }
  __syncthreads();
}

// ---------------- one MHA layer via mfma_f32_16x16x32_bf16 (layout verified R6-R10) ----------------
// Activations in LDS. 1024 threads: t<512 stage K+V from kvsrc; t>=512 stage Q from qsrc.
// Compute phase: h is the OUTER rolled loop; per h only 2 B-operands + 2 accumulators are
// live (peak regs ~70 << 128 cap) - accumulation over all keys completes within one h,
// then dumps straight to sO. Sᵀ = K·Qᵀ; exp(Sᵀ) feeds PV's A from registers; V col3=1 -> denom.
__device__ __forceinline__ void mha_mfma(
    const float* qsrc, const float* kvsrc, float* dst, float* outv,
    const float* __restrict__ w_in, const float* __restrict__ b_in,
    const float* __restrict__ w_out, const float* __restrict__ b_out,
    uint4* skA, uint4* sqQ, unsigned short* svB, float* sO, int t)
{
  __syncthreads();   // previous layer's consumers/writers of all LDS regions are done

  const int p = t & 511;
  if (t < 512) {
    // ---- stage K and V for point p from kvsrc row ----
    float xr[EMB];
    {
      const float4* r4 = (const float4*)(kvsrc + p * EMB);
      float4 r0 = r4[0], r1 = r4[1], r2 = r4[2];
      xr[0]=r0.x; xr[1]=r0.y; xr[2]=r0.z; xr[3]=r0.w;
      xr[4]=r1.x; xr[5]=r1.y; xr[6]=r1.z; xr[7]=r1.w;
      xr[8]=r2.x; xr[9]=r2.y; xr[10]=r2.z; xr[11]=r2.w;
    }
    const int kg = p >> 5, oddt = (p >> 4) & 1, kap = p & 15;   // 32-key group / half / slot
    uint2* skA2 = (uint2*)skA;
    const int g = p & 31, odd = g >> 4, sub = g & 15;
    const int q4 = sub >> 2, jj = (sub & 3) + 4 * odd;
    #pragma unroll
    for (int h = 0; h < NHD; ++h) {
      float k0 = b_in[EMB + h*3+0],   k1 = b_in[EMB + h*3+1],   k2 = b_in[EMB + h*3+2];
      float v0 = b_in[2*EMB + h*3+0], v1 = b_in[2*EMB + h*3+1], v2 = b_in[2*EMB + h*3+2];
      #pragma unroll
      for (int f = 0; f < EMB; ++f) {
        float x = xr[f];
        k0 = fmaf(x, w_in[(EMB + h*3+0) * EMB + f], k0);
        k1 = fmaf(x, w_in[(EMB + h*3+1) * EMB + f], k1);
        k2 = fmaf(x, w_in[(EMB + h*3+2) * EMB + f], k2);
        v0 = fmaf(x, w_in[(2*EMB + h*3+0) * EMB + f], v0);
        v1 = fmaf(x, w_in[(2*EMB + h*3+1) * EMB + f], v1);
        v2 = fmaf(x, w_in[(2*EMB + h*3+2) * EMB + f], v2);
      }
      skA2[((kg * NHD + h) * 16 + kap) * 2 + oddt] =
          make_uint2(bf16rne(k0) | (bf16rne(k1) << 16), bf16rne(k2));
      svB[(((kg * NHD + h) * 4 + q4) * 4 + 0) * 8 + jj] = (unsigned short)bf16rne(v0);
      svB[(((kg * NHD + h) * 4 + q4) * 4 + 1) * 8 + jj] = (unsigned short)bf16rne(v1);
      svB[(((kg * NHD + h) * 4 + q4) * 4 + 2) * 8 + jj] = (unsigned short)bf16rne(v2);
      svB[(((kg * NHD + h) * 4 + q4) * 4 + 3) * 8 + jj] = (unsigned short)0x3F80u; // 1.0 -> denom
    }
  } else {
    // ---- stage Q (scaled) for point p from qsrc row ----
    float xr[EMB];
    {
      const float4* r4 = (const float4*)(qsrc + p * EMB);
      float4 r0 = r4[0], r1 = r4[1], r2 = r4[2];
      xr[0]=r0.x; xr[1]=r0.y; xr[2]=r0.z; xr[3]=r0.w;
      xr[4]=r1.x; xr[5]=r1.y; xr[6]=r1.z; xr[7]=r1.w;
      xr[8]=r2.x; xr[9]=r2.y; xr[10]=r2.z; xr[11]=r2.w;
    }
    const float qs = 0.5773502691896258f * 1.4426950408889634f; // 1/sqrt(3)*log2(e)
    const int kt = p >> 4, kap = p & 15;
    #pragma unroll
    for (int h = 0; h < NHD; ++h) {
      float q0 = b_in[h*3+0], q1 = b_in[h*3+1], q2 = b_in[h*3+2];
      #pragma unroll
      for (int f = 0; f < EMB; ++f) {
        float x = xr[f];
        q0 = fmaf(x, w_in[(h*3+0) * EMB + f], q0);
        q1 = fmaf(x, w_in[(h*3+1) * EMB + f], q1);
        q2 = fmaf(x, w_in[(h*3+2) * EMB + f], q2);
      }
      q0 *= qs; q1 *= qs; q2 *= qs;
      sqQ[(kt * NHD + h) * 16 + kap] =
          make_uint4(bf16rne(q0) | (bf16rne(q1) << 16), bf16rne(q2), 0u, 0u);
    }
  }
  __syncthreads();

  const int lane = t & 63, wv = t >> 6;          // wv 0..15
  const int lq = lane >> 4, ln = lane & 15;
  const uint4* svB4 = (const uint4*)svB;
  const uint2* sqQ2 = (const uint2*)sqQ;

  #pragma unroll 1
  for (int h = 0; h < NHD; ++h) {
    // ---- B operands (Qᵀ) for this wave's 2 row-tiles; quads >= 1 zeroed ----
    U16 b0, b1;
    {
      uint2 qa = sqQ2[(((wv * 2 + 0) * NHD + h) * 16 + ln) * 2];
      uint2 qb = sqQ2[(((wv * 2 + 1) * NHD + h) * 16 + ln) * 2];
      b0.u = make_uint4(lq == 0 ? qa.x : 0u, lq == 0 ? qa.y : 0u, 0u, 0u);
      b1.u = make_uint4(lq == 0 ? qb.x : 0u, lq == 0 ? qb.y : 0u, 0u, 0u);
    }
    floatx4 acc0 = {0.f, 0.f, 0.f, 0.f};
    floatx4 acc1 = {0.f, 0.f, 0.f, 0.f};

    for (int kg = 0; kg < 16; ++kg) {
      uint4 kp = skA[(kg * NHD + h) * 16 + ln];                  // K even+odd pair (bcast x4)
      U16 vf; vf.u = svB4[((kg * NHD + h) * 4 + lq) * 4 + (ln & 3)];
      U16 fe; fe.u = make_uint4(kp.x, kp.y, 0u, 0u);             // even-tile A frag
      U16 fo; fo.u = make_uint4(kp.z, kp.w, 0u, 0u);             // odd-tile A frag
      floatx4 zc = {0.f, 0.f, 0.f, 0.f};
      // row-tile 0
      {
        floatx4 se = __builtin_amdgcn_mfma_f32_16x16x32_bf16(fe.s, b0.s, zc, 0, 0, 0);
        floatx4 so = __builtin_amdgcn_mfma_f32_16x16x32_bf16(fo.s, b0.s, zc, 0, 0, 0);
        unsigned p0 = __float_as_uint(__builtin_amdgcn_exp2f(se[0]));
        unsigned p1 = __float_as_uint(__builtin_amdgcn_exp2f(se[1]));
        unsigned p2 = __float_as_uint(__builtin_amdgcn_exp2f(se[2]));
        unsigned p3 = __float_as_uint(__builtin_amdgcn_exp2f(se[3]));
        unsigned p4 = __float_as_uint(__builtin_amdgcn_exp2f(so[0]));
        unsigned p5 = __float_as_uint(__builtin_amdgcn_exp2f(so[1]));
        unsigned p6 = __float_as_uint(__builtin_amdgcn_exp2f(so[2]));
        unsigned p7 = __float_as_uint(__builtin_amdgcn_exp2f(so[3]));
        U16 pf;
        pf.u.x = __builtin_amdgcn_perm(p1, p0, 0x07060302u);
        pf.u.y = __builtin_amdgcn_perm(p3, p2, 0x07060302u);
        pf.u.z = __builtin_amdgcn_perm(p5, p4, 0x07060302u);
        pf.u.w = __builtin_amdgcn_perm(p7, p6, 0x07060302u);
        acc0 = __builtin_amdgcn_mfma_f32_16x16x32_bf16(pf.s, vf.s, acc0, 0, 0, 0);
      }
      // row-tile 1
      {
        floatx4 se = __builtin_amdgcn_mfma_f32_16x16x32_bf16(fe.s, b1.s, zc, 0, 0, 0);
        floatx4 so = __builtin_amdgcn_mfma_f32_16x16x32_bf16(fo.s, b1.s, zc, 0, 0, 0);
        unsigned p0 = __float_as_uint(__builtin_amdgcn_exp2f(se[0]));
        unsigned p1 = __float_as_uint(__builtin_amdgcn_exp2f(se[1]));
        unsigned p2 = __float_as_uint(__builtin_amdgcn_exp2f(se[2]));
        unsigned p3 = __float_as_uint(__builtin_amdgcn_exp2f(se[3]));
        unsigned p4 = __float_as_uint(__builtin_amdgcn_exp2f(so[0]));
        unsigned p5 = __float_as_uint(__builtin_amdgcn_exp2f(so[1]));
        unsigned p6 = __float_as_uint(__builtin_amdgcn_exp2f(so[2]));
        unsigned p7 = __float_as_uint(__builtin_amdgcn_exp2f(so[3]));
        U16 pf;
        pf.u.x = __builtin_amdgcn_perm(p1, p0, 0x07060302u);
        pf.u.y = __builtin_amdgcn_perm(p3, p2, 0x07060302u);
        pf.u.z = __builtin_amdgcn_perm(p5, p4, 0x07060302u);
        pf.u.w = __builtin_amdgcn_perm(p7, p6, 0x07060302u);
        acc1 = __builtin_amdgcn_mfma_f32_16x16x32_bf16(pf.s, vf.s, acc1, 0, 0, 0);
      }
    }

    // ---- dump this head's O (C-layout, cols 0..3 valid) to per-row layout in LDS ----
    if (ln < 4) {
      #pragma unroll
      for (int r = 0; r < 4; ++r) {
        sO[((wv * 2 + 0) * 16 + lq * 4 + r) * 16 + h * 4 + ln] = acc0[r];
        sO[((wv * 2 + 1) * 16 + lq * 4 + r) * 16 + h * 4 + ln] = acc1[r];
      }
    }
  }
  __syncthreads();

  // ---- normalize + out-projection for point p (t<512 only); write to dst or outv ----
  if (t < 512) {
    const float4* sr = (const float4*)(sO + p * 16);
    float o[EMB];
    #pragma unroll
    for (int h = 0; h < NHD; ++h) {
      float4 Oh = sr[h];
      float inv = 1.0f / fmaxf(Oh.w, 1e-20f);   // inert guard
      o[h*3+0] = Oh.x * inv; o[h*3+1] = Oh.y * inv; o[h*3+2] = Oh.z * inv;
    }
    float r[EMB];
    #pragma unroll
    for (int e = 0; e < EMB; ++e) {
      float s = b_out[e];
      #pragma unroll
      for (int f = 0; f < EMB; ++f) s = fmaf(o[f], w_out[e * EMB + f], s);
      r[e] = s;
    }
    if (dst) {
      float4* d4 = (float4*)(dst + p * EMB);
      d4[0] = make_float4(r[0], r[1], r[2],  r[3]);
      d4[1] = make_float4(r[4], r[5], r[6],  r[7]);
      d4[2] = make_float4(r[8], r[9], r[10], r[11]);
    } else {
      #pragma unroll
      for (int e = 0; e < EMB; ++e) outv[e] = r[e];
    }
  }
}

__global__ __launch_bounds__(1024, 4)
void pcr_kernel(const float* __restrict__ x_orig, const float* __restrict__ y_orig,
                const float* __restrict__ lin_in_w,  const float* __restrict__ lin_in_b,
                const float* __restrict__ lin_in2_w, const float* __restrict__ lin_in2_b,
                const float* __restrict__ attn_in_w,  const float* __restrict__ attn_in_b,
                const float* __restrict__ attn_out_w, const float* __restrict__ attn_out_b,
                const float* __restrict__ attn2_in_w,  const float* __restrict__ attn2_in_b,
                const float* __restrict__ attn2_out_w, const float* __restrict__ attn2_out_b,
                const float* __restrict__ cross_in_w,  const float* __restrict__ cross_in_b,
                const float* __restrict__ cross_out_w, const float* __restrict__ cross_out_b,
                const float* __restrict__ lin_out_w, const float* __restrict__ lin_out_b,
                float* __restrict__ out)
{
  __shared__ __align__(16) float sX[PTS * EMB];                        // 24 KB x-path activations
  __shared__ __align__(16) float sY[PTS * EMB];                        // 24 KB y-path activations
  __shared__ __align__(16) uint4 skA[16 * NHD * 16];                   // 16 KB K pairs
  __shared__ __align__(16) uint4 sqQ[32 * NHD * 16];                   // 32 KB Q frags
  __shared__ __align__(16) unsigned short svB[16 * NHD * 4 * 4 * 8];   // 16 KB V frags
  __shared__ __align__(16) float sO[PTS * 16];                         // 32 KB O rows
  __shared__ float sred[16 * 12];

  const int b = blockIdx.x;
  const int t = threadIdx.x;
  const int p = t & 511;
  const bool own = (t < 512);
  const int base = (b * PTS + p) * 3;

  // ---- center x and y (per-batch mean; only t<512 contribute to sums) ----
  float x3[3], ymean[3];
  {
    float xl[3], yl[3];
    #pragma unroll
    for (int i = 0; i < 3; ++i) { xl[i] = x_orig[base + i]; yl[i] = y_orig[base + i]; }
    float r6[6];
    #pragma unroll
    for (int i = 0; i < 3; ++i) {
      r6[i]     = own ? xl[i] : 0.f;
      r6[3 + i] = own ? yl[i] : 0.f;
    }
    block_reduce<6, 16>(r6, sred, t);
    float y3[3];
    #pragma unroll
    for (int i = 0; i < 3; ++i) {
      x3[i]    = xl[i] - r6[i] * (1.f / PTS);
      ymean[i] = r6[3 + i] * (1.f / PTS);
      y3[i]    = yl[i] - ymean[i];
    }
    // ---- input linears (3 -> 12): t<512 write sX from x; t>=512 write sY from y ----
    const float* w = own ? lin_in_w : lin_in2_w;
    const float* bi = own ? lin_in_b : lin_in2_b;
    const float* src = own ? x3 : y3;
    float* dst = own ? sX : sY;
    float r[EMB];
    #pragma unroll
    for (int e = 0; e < EMB; ++e) {
      float s = bi[e];
      #pragma unroll
      for (int i = 0; i < 3; ++i) s = fmaf(src[i], w[e * 3 + i], s);
      r[e] = s;
    }
    float4* d4 = (float4*)(dst + p * EMB);
    d4[0] = make_float4(r[0], r[1], r[2],  r[3]);
    d4[1] = make_float4(r[4], r[5], r[6],  r[7]);
    d4[2] = make_float4(r[8], r[9], r[10], r[11]);
  }

  // ---- three attention layers (activations carried in LDS) ----
  float o12[EMB];   // defined only for own threads after L3
  // L1 self(x): q,kv from sX; out -> sX
  mha_mfma(sX, sX, sX, nullptr, attn_in_w,  attn_in_b,  attn_out_w,  attn_out_b,
           skA, sqQ, svB, sO, t);
  // L2 self(y): q,kv from sY; out -> sY
  mha_mfma(sY, sY, sY, nullptr, attn2_in_w, attn2_in_b, attn2_out_w, attn2_out_b,
           skA, sqQ, svB, sO, t);
  // L3 cross(q=x1, kv=y1): out kept in registers (t<512)
  mha_mfma(sX, sY, nullptr, o12, cross_in_w, cross_in_b, cross_out_w, cross_out_b,
           skA, sqQ, svB, sO, t);

  // ---- output linear (12 -> 3); bp = coords + x ; Kabsch reduce ----
  float r12[12];
  if (own) {
    float bp[3];
    #pragma unroll
    for (int d = 0; d < 3; ++d) {
      float c = lin_out_b[d];
      #pragma unroll
      for (int e = 0; e < EMB; ++e) c = fmaf(o12[e], lin_out_w[d * EMB + e], c);
      bp[d] = c + x3[d];
    }
    #pragma unroll
    for (int i = 0; i < 3; ++i)
      #pragma unroll
      for (int j = 0; j < 3; ++j) r12[i * 3 + j] = x3[i] * bp[j];
    #pragma unroll
    for (int j = 0; j < 3; ++j) r12[9 + j] = bp[j];
  } else {
    #pragma unroll
    for (int i = 0; i < 12; ++i) r12[i] = 0.f;
  }
  block_reduce<12, 16>(r12, sred, t);

  if (own) {
    float cA[3];
    #pragma unroll
    for (int j = 0; j < 3; ++j) cA[j] = r12[9 + j] * (1.f / PTS);

    // ---- R = polar factor of H via determinant-scaled Newton (== U @ Vt) ----
    float a00 = r12[0], a01 = r12[1], a02 = r12[2];
    float a10 = r12[3], a11 = r12[4], a12_ = r12[5];
    float a20 = r12[6], a21 = r12[7], a22 = r12[8];

    float c0 = fabsf(a00) + fabsf(a10) + fabsf(a20);
    float c1 = fabsf(a01) + fabsf(a11) + fabsf(a21);
    float c2 = fabsf(a02) + fabsf(a12_) + fabsf(a22);
    float r0 = fabsf(a00) + fabsf(a01) + fabsf(a02);
    float r1 = fabsf(a10) + fabsf(a11) + fabsf(a12_);
    float r2 = fabsf(a20) + fabsf(a21) + fabsf(a22);
    float fsc = rsqrtf(fmaxf(c0, fmaxf(c1, c2)) * fmaxf(r0, fmaxf(r1, r2)) + 1e-30f);
    a00 *= fsc; a01 *= fsc; a02 *= fsc;
    a10 *= fsc; a11 *= fsc; a12_ *= fsc;
    a20 *= fsc; a21 *= fsc; a22 *= fsc;

    #pragma unroll 1
    for (int it = 0; it < 12; ++it) {
      float C00 = a11*a22 - a12_*a21;
      float C01 = a12_*a20 - a10*a22;
      float C02 = a10*a21 - a11*a20;
      float C10 = a02*a21 - a01*a22;
      float C11 = a00*a22 - a02*a20;
      float C12 = a01*a20 - a00*a21;
      float C20 = a01*a12_ - a02*a11;
      float C21 = a02*a10 - a00*a12_;
      float C22 = a00*a11 - a01*a10;
      float det = a00*C00 + a01*C01 + a02*C02;
      float g  = 1.0f / cbrtf(fabsf(det) + 1e-30f);
      float dg = det * g;
      dg = copysignf(fmaxf(fabsf(dg), 1e-25f), dg);   // inert guard
      float id = 0.5f / dg;
      float gh = 0.5f * g;
      a00 = gh*a00 + C00*id; a01 = gh*a01 + C01*id; a02 = gh*a02 + C02*id;
      a10 = gh*a10 + C10*id; a11 = gh*a11 + C11*id; a12_ = gh*a12_ + C12*id;
      a20 = gh*a20 + C20*id; a21 = gh*a21 + C21*id; a22 = gh*a22 + C22*id;
    }

    // ---- out = x @ R + t + y_translate ----
    float o0 = fmaf(x3[0], a00, fmaf(x3[1], a10, fmaf(x3[2], a20, cA[0] + ymean[0])));
    float o1 = fmaf(x3[0], a01, fmaf(x3[1], a11, fmaf(x3[2], a21, cA[1] + ymean[1])));
    float o2 = fmaf(x3[0], a02, fmaf(x3[1], a12_, fmaf(x3[2], a22, cA[2] + ymean[2])));
    out[base + 0] = o0;
    out[base + 1] = o1;
    out[base + 2] = o2;
  }
}

extern "C" void kernel_launch(void* const* d_in, const int* in_sizes, int n_in,
                              void* d_out, int out_size, void* d_ws, size_t ws_size,
                              hipStream_t stream) {
  const float* p[20];
  for (int i = 0; i < 20; ++i) p[i] = (const float*)d_in[i];
  pcr_kernel<<<dim3(NB), dim3(1024), 0, stream>>>(
      p[0], p[1], p[2], p[3], p[4], p[5], p[6], p[7], p[8], p[9],
      p[10], p[11], p[12], p[13], p[14], p[15], p[16], p[17], p[18], p[19],
      (float*)d_out);
}